// Round 1
// baseline (126.990 us; speedup 1.0000x reference)
//
#include <hip/hip_runtime.h>
#include <math.h>

// DifferentiableLassoSelector: B=65536, n=256, h=32.
// p = 6553.6 - Z^T y  > 0 elementwise (40-sigma margin) => projected-gradient
// QP stays at lam=0 exactly => y_hat = 0 exactly. We compute Z / Z^T y honestly,
// test min(p) >= 0 on device, and take the exact zero shortcut; the general
// solver path exists below and is flag-guarded (early-exit when not needed).

#define NF 256
#define HID 32
#define BATCHN 65536
#define NBLK 1024
#define ROWS_PER_BLK (BATCHN / NBLK)   // 64
#define ALPHA_BF 6553.6f               // ALPHA * BATCH
#define JITTERF 1e-4f
#define QP_ITERS_N 500
#define K2C 2.8853900817779268f        // 2*log2(e): exp2(K2C*u) = e^{2u}

// ws float layout (needs ~1.91 MB):
// 0      : part  [NBLK][NF]   262144
// 262144 : part2 [64][NF]      16384
// 278528 : p     [NF]
// 278784 : flag  (1.0 => zero path)
// 278800 : lam   [NF]
// 280576 : Q     [NF*NF]
// 346112 : L     [NF*NF]
// 411648 : Qe    [NF*NF]      (end 477184 floats)

#if __has_builtin(__builtin_amdgcn_exp2f)
__device__ __forceinline__ float fexp2(float x) { return __builtin_amdgcn_exp2f(x); }
#else
__device__ __forceinline__ float fexp2(float x) { return exp2f(x); }
#endif
#if __has_builtin(__builtin_amdgcn_rcpf)
__device__ __forceinline__ float frcp(float x) { return __builtin_amdgcn_rcpf(x); }
#else
__device__ __forceinline__ float frcp(float x) { return 1.0f / x; }
#endif

// ---------------- main heavy kernel: Z^T y partials (Z never materialized) ---
__global__ __launch_bounds__(256, 2) void zty_kernel(
    const float* __restrict__ x, const float* __restrict__ y,
    const float* __restrict__ W1, const float* __restrict__ b1,
    const float* __restrict__ W2, const float* __restrict__ b2,
    float* __restrict__ part)
{
  const int n = threadIdx.x;            // feature column, 0..255
  const int blk = blockIdx.x;
  // weights register-resident: 96 VGPRs
  float w1s[HID], b1s[HID], w2[HID];
  float base = b2[n];
  #pragma unroll
  for (int h = 0; h < HID; ++h) {
    w1s[h] = W1[n * HID + h] * K2C;
    b1s[h] = b1[n * HID + h] * K2C;
    w2[h]  = W2[n * HID + h];
    base  += w2[h];                     // sum_h W2 (tanh = 1 - 2/(e+1) split)
  }
  const int b0 = blk * ROWS_PER_BLK;
  const float* xp = x + (size_t)b0 * NF + n;
  float xv = xp[0];
  float yv = y[b0];
  float zty = 0.f;
  for (int r = 0; r < ROWS_PER_BLK; ++r) {
    // prefetch next row (clamped index keeps loads in-bounds)
    int rn = (r + 1 < ROWS_PER_BLK) ? (r + 1) : r;
    float xnext = xp[(size_t)rn * NF];
    float ynext = y[b0 + rn];
    float a0 = 0.f, a1 = 0.f, a2 = 0.f, a3 = 0.f;
    #pragma unroll
    for (int h = 0; h < HID; h += 4) {
      float u0 = fmaf(xv, w1s[h + 0], b1s[h + 0]);
      float u1 = fmaf(xv, w1s[h + 1], b1s[h + 1]);
      float u2 = fmaf(xv, w1s[h + 2], b1s[h + 2]);
      float u3 = fmaf(xv, w1s[h + 3], b1s[h + 3]);
      float e0 = fexp2(u0), e1 = fexp2(u1), e2 = fexp2(u2), e3 = fexp2(u3);
      a0 = fmaf(w2[h + 0], frcp(e0 + 1.f), a0);
      a1 = fmaf(w2[h + 1], frcp(e1 + 1.f), a1);
      a2 = fmaf(w2[h + 2], frcp(e2 + 1.f), a2);
      a3 = fmaf(w2[h + 3], frcp(e3 + 1.f), a3);
    }
    float z = fmaf(-2.f, (a0 + a1) + (a2 + a3), base);  // Z[b,n]
    zty = fmaf(z, yv, zty);
    xv = xnext; yv = ynext;
  }
  part[(size_t)blk * NF + n] = zty;     // deterministic two-stage reduction
}

// ---------------- reductions (fixed order => deterministic) ------------------
__global__ __launch_bounds__(256) void reduce1(const float* __restrict__ part,
                                               float* __restrict__ part2)
{
  int n = threadIdx.x, j = blockIdx.x;  // 64 blocks
  float s = 0.f;
  for (int k = 0; k < 16; ++k) s += part[(size_t)(j * 16 + k) * NF + n];
  part2[(size_t)j * NF + n] = s;
}

__global__ __launch_bounds__(256) void reduce2(const float* __restrict__ part2,
                                               float* __restrict__ p,
                                               float* __restrict__ flag)
{
  int n = threadIdx.x;
  float s = 0.f;
  for (int k = 0; k < 64; ++k) s += part2[(size_t)k * NF + n];
  float pv = ALPHA_BF - s;
  p[n] = pv;
  __shared__ float sm[NF];
  sm[n] = pv;
  __syncthreads();
  for (int off = 128; off > 0; off >>= 1) {
    if (n < off) sm[n] = fminf(sm[n], sm[n + off]);
    __syncthreads();
  }
  if (n == 0) flag[0] = (sm[0] >= 0.f) ? 1.f : 0.f;  // p>=0 => lam stays 0 exactly
}

// ---------------- general path (flag-guarded; unreachable for these inputs) --
__global__ __launch_bounds__(256) void qinit(const float* __restrict__ flag,
                                             float* __restrict__ Q)
{
  if (flag[0] >= 0.5f) return;
  int idx = blockIdx.x * 256 + threadIdx.x;   // 256 blocks
  int i = idx >> 8, j = idx & 255;
  Q[idx] = (i == j) ? JITTERF : 0.f;
}

__global__ __launch_bounds__(256) void qacc(
    const float* __restrict__ x,
    const float* __restrict__ W1, const float* __restrict__ b1,
    const float* __restrict__ W2, const float* __restrict__ b2,
    const float* __restrict__ flag, float* __restrict__ Q)
{
  if (flag[0] >= 0.5f) return;
  __shared__ float zsh[ROWS_PER_BLK * NF];    // 64 KiB
  const int t = threadIdx.x;
  float w1s[HID], b1s[HID], w2[HID];
  float base = b2[t];
  #pragma unroll
  for (int h = 0; h < HID; ++h) {
    w1s[h] = W1[t * HID + h] * K2C;
    b1s[h] = b1[t * HID + h] * K2C;
    w2[h]  = W2[t * HID + h];
    base  += w2[h];
  }
  const int b0 = blockIdx.x * ROWS_PER_BLK;
  for (int r = 0; r < ROWS_PER_BLK; ++r) {
    float xv = x[(size_t)(b0 + r) * NF + t];
    float acc = 0.f;
    #pragma unroll
    for (int h = 0; h < HID; ++h) {
      float u = fmaf(xv, w1s[h], b1s[h]);
      acc = fmaf(w2[h], frcp(fexp2(u) + 1.f), acc);
    }
    zsh[r * NF + t] = fmaf(-2.f, acc, base);
  }
  __syncthreads();
  for (int j = 0; j < NF; ++j) {
    float s = 0.f;
    for (int r = 0; r < ROWS_PER_BLK; ++r) s += zsh[r * NF + t] * zsh[r * NF + j];
    atomicAdd(&Q[t * NF + j], s);
  }
}

__global__ __launch_bounds__(256) void solver_kernel(
    const float* __restrict__ p, const float* __restrict__ flag,
    const float* __restrict__ Q, float* __restrict__ L, float* __restrict__ Qe,
    float* __restrict__ lamg, float* __restrict__ dout_lam)
{
  const int t = threadIdx.x;
  if (flag[0] >= 0.5f) {                 // exact zero path
    dout_lam[t] = 0.f;
    lamg[t] = 0.f;
    return;
  }
  __shared__ float sm[NF];
  __shared__ float lam_s[NF];
  for (int i = 0; i < NF; ++i) L[i * NF + t] = (t <= i) ? Q[i * NF + t] : 0.f;
  __syncthreads();
  for (int k = 0; k < NF; ++k) {         // right-looking Cholesky
    if (t == 0) L[k * NF + k] = sqrtf(L[k * NF + k]);
    __syncthreads();
    float lkk = L[k * NF + k];
    if (t > k) L[t * NF + k] /= lkk;
    __syncthreads();
    if (t > k) {
      float ltk = L[t * NF + k];
      for (int i = k + 1; i <= t; ++i) L[t * NF + i] -= ltk * L[i * NF + k];
    }
    __syncthreads();
  }
  for (int i = 0; i < NF; ++i) {         // Qe = L L^T
    int m = (i < t) ? i : t;
    float s = 0.f;
    for (int k = 0; k <= m; ++k) s += L[i * NF + k] * L[t * NF + k];
    Qe[i * NF + t] = s;
  }
  __syncthreads();
  lam_s[t] = 1.f;                        // power iteration for lambda_max
  __syncthreads();
  float lmax = 1.f;
  for (int it = 0; it < 256; ++it) {
    float s = 0.f;
    for (int k = 0; k < NF; ++k) s += Qe[t * NF + k] * lam_s[k];
    sm[t] = s * s;
    __syncthreads();
    for (int off = 128; off > 0; off >>= 1) {
      if (t < off) sm[t] += sm[t + off];
      __syncthreads();
    }
    float nrm = sqrtf(sm[0]);
    __syncthreads();
    lam_s[t] = s / nrm;
    lmax = nrm;
    __syncthreads();
  }
  float step = 1.0f / lmax;
  lam_s[t] = 0.f;
  __syncthreads();
  float pv = p[t];
  for (int it = 0; it < QP_ITERS_N; ++it) {
    float s = 0.f;
    for (int k = 0; k < NF; ++k) s += Qe[t * NF + k] * lam_s[k];
    float ln = fmaxf(lam_s[t] - step * (s + pv), 0.f);
    __syncthreads();
    lam_s[t] = ln;
    __syncthreads();
  }
  dout_lam[t] = lam_s[t];
  lamg[t] = lam_s[t];
}

__global__ __launch_bounds__(256) void yhat_kernel(
    const float* __restrict__ x,
    const float* __restrict__ W1, const float* __restrict__ b1,
    const float* __restrict__ W2, const float* __restrict__ b2,
    const float* __restrict__ flag, const float* __restrict__ lamg,
    float* __restrict__ yhat)
{
  const int b = blockIdx.x * 256 + threadIdx.x;
  if (flag[0] >= 0.5f) { yhat[b] = 0.f; return; }   // Z @ 0 == 0 exactly
  __shared__ float lam_s[NF];
  lam_s[threadIdx.x] = lamg[threadIdx.x];
  __syncthreads();
  float acc = 0.f;
  for (int n = 0; n < NF; ++n) {
    float xv = x[(size_t)b * NF + n];
    float zacc = 0.f, base = b2[n];
    for (int h = 0; h < HID; ++h) {
      float w2h = W2[n * HID + h];
      base += w2h;
      float u = fmaf(xv, W1[n * HID + h] * K2C, b1[n * HID + h] * K2C);
      zacc = fmaf(w2h, frcp(fexp2(u) + 1.f), zacc);
    }
    acc = fmaf(fmaf(-2.f, zacc, base), lam_s[n], acc);
  }
  yhat[b] = acc;
}

// ---------------- host launcher ---------------------------------------------
extern "C" void kernel_launch(void* const* d_in, const int* in_sizes, int n_in,
                              void* d_out, int out_size, void* d_ws, size_t ws_size,
                              hipStream_t stream) {
  const float* x  = (const float*)d_in[0];
  const float* y  = (const float*)d_in[1];
  const float* W1 = (const float*)d_in[2];
  const float* b1 = (const float*)d_in[3];
  const float* W2 = (const float*)d_in[4];
  const float* b2 = (const float*)d_in[5];
  float* out = (float*)d_out;           // [0,65536): y_hat ; [65536,65792): lam
  float* ws  = (float*)d_ws;

  float* part  = ws;
  float* part2 = ws + 262144;
  float* p     = ws + 278528;
  float* flag  = ws + 278784;
  float* lam   = ws + 278800;
  float* Q     = ws + 280576;
  float* L     = ws + 346112;
  float* Qe    = ws + 411648;

  zty_kernel<<<NBLK, 256, 0, stream>>>(x, y, W1, b1, W2, b2, part);
  reduce1<<<64, 256, 0, stream>>>(part, part2);
  reduce2<<<1, 256, 0, stream>>>(part2, p, flag);
  qinit<<<256, 256, 0, stream>>>(flag, Q);
  qacc<<<NBLK, 256, 0, stream>>>(x, W1, b1, W2, b2, flag, Q);
  solver_kernel<<<1, 256, 0, stream>>>(p, flag, Q, L, Qe, lam, out + BATCHN);
  yhat_kernel<<<BATCHN / 256, 256, 0, stream>>>(x, W1, b1, W2, b2, flag, lam, out);
}